// Round 2
// baseline (537.144 us; speedup 1.0000x reference)
//
#include <hip/hip_runtime.h>

#define NN 4096
#define HH 32
#define DD 128
#define MM 16
#define PP 8192

__device__ __forceinline__ float4 ld4(const float* p) { return *(const float4*)p; }
__device__ __forceinline__ float dot4f(float4 a, float4 b) {
  return a.x * b.x + a.y * b.y + a.z * b.z + a.w * b.w;
}
__device__ __forceinline__ void accumv(float* o, float e, float4 a, float4 b,
                                       float4 c, float4 d) {
  o[0] += e * a.x;  o[1] += e * a.y;  o[2] += e * a.z;  o[3] += e * a.w;
  o[4] += e * b.x;  o[5] += e * b.y;  o[6] += e * b.z;  o[7] += e * b.w;
  o[8] += e * c.x;  o[9] += e * c.y;  o[10] += e * c.z; o[11] += e * c.w;
  o[12] += e * d.x; o[13] += e * d.y; o[14] += e * d.z; o[15] += e * d.w;
}

// ---------------------------------------------------------------- K1: RMS inv
__global__ void k1_rms(const float* __restrict__ X, float* __restrict__ inv) {
  const int m = blockIdx.x;
  const int tid = threadIdx.x;
  float s = 0.f;
#pragma unroll
  for (int i = 0; i < 16; ++i) {
    float v = X[(size_t)m * NN + i * 256 + tid];
    s += v * v;
  }
#pragma unroll
  for (int off = 1; off < 64; off <<= 1) s += __shfl_xor(s, off, 64);
  __shared__ float red[4];
  if ((tid & 63) == 0) red[tid >> 6] = s;
  __syncthreads();
  if (tid == 0) {
    float t = red[0] + red[1] + red[2] + red[3];
    inv[m] = rsqrtf(t * (1.0f / (float)NN));
  }
}

// ------------------------------------------------- K2: QKV quarter partials
// grid 1536 = 3 mats x 4 k-quarters x 128 row-groups(32 rows). block 256.
// wave covers k-slice of 256 within its quarter; lane=(m4,g16): 4 m x 16 k.
// X in registers (read once per wave); W streamed coalesced, read exactly once.
__global__ __launch_bounds__(256, 4) void k2_qkv(
    const float* __restrict__ X, const float* __restrict__ Wq,
    const float* __restrict__ Wk, const float* __restrict__ Wv,
    float* __restrict__ c_part) {
  __shared__ float lds_c[4][32][18];
  const int b = blockIdx.x;
  const int mat = b >> 9;
  const int rem = b & 511;
  const int qt = rem >> 7;
  const int jg = rem & 127;
  const float* W = (mat == 0) ? Wq : (mat == 1) ? Wk : Wv;
  const int tid = threadIdx.x;
  const int wave = tid >> 6;
  const int lane = tid & 63;
  const int m4 = lane & 3;
  const int g = lane >> 2;
  const int kbase = qt * 1024 + wave * 256 + g * 16;

  float4 xr[4][4];  // [mi][j4]; m = mi*4 + m4
#pragma unroll
  for (int mi = 0; mi < 4; ++mi) {
    const float* xp = X + (size_t)(mi * 4 + m4) * NN + kbase;
#pragma unroll
    for (int j = 0; j < 4; ++j) xr[mi][j] = ld4(xp + j * 4);
  }

  const int j0 = jg * 32;
  for (int grp = 0; grp < 8; ++grp) {
    float acc[4][4];  // [row r][mi]
#pragma unroll
    for (int r = 0; r < 4; ++r)
#pragma unroll
      for (int mi = 0; mi < 4; ++mi) acc[r][mi] = 0.f;
#pragma unroll
    for (int r = 0; r < 4; ++r) {
      const float* wp = W + (size_t)(j0 + grp * 4 + r) * NN + kbase;
      float4 w0 = ld4(wp);
      float4 w1 = ld4(wp + 4);
      float4 w2 = ld4(wp + 8);
      float4 w3 = ld4(wp + 12);
#pragma unroll
      for (int mi = 0; mi < 4; ++mi)
        acc[r][mi] = acc[r][mi] + dot4f(xr[mi][0], w0) + dot4f(xr[mi][1], w1) +
                     dot4f(xr[mi][2], w2) + dot4f(xr[mi][3], w3);
    }
#pragma unroll
    for (int off = 4; off < 64; off <<= 1)
#pragma unroll
      for (int r = 0; r < 4; ++r)
#pragma unroll
        for (int mi = 0; mi < 4; ++mi)
          acc[r][mi] += __shfl_xor(acc[r][mi], off, 64);
    if (g == 0) {
#pragma unroll
      for (int r = 0; r < 4; ++r)
#pragma unroll
        for (int mi = 0; mi < 4; ++mi)
          lds_c[wave][grp * 4 + r][mi * 4 + m4] = acc[r][mi];
    }
  }
  __syncthreads();
  // combine 4 waves' k-slices -> quarter partial, store [mat*4+qt][m][4096]
#pragma unroll
  for (int i = 0; i < 2; ++i) {
    const int idx = i * 256 + tid;
    const int j = idx & 31;
    const int m = idx >> 5;
    float s = lds_c[0][j][m] + lds_c[1][j][m] + lds_c[2][j][m] + lds_c[3][j][m];
    c_part[(((size_t)(mat * 4 + qt) * 16 + m) << 12) + (j0 + j)] = s;
  }
}

// ------------------------------------------------- K3: attention partials
// grid (33, 32). chunk<32: 256 cached p (64 per wave); chunk 32: appended 16.
// NO LDS: K/V rows touched by exactly one wave -> stream from global.
// lane=(m8,g8): 2 m x 16 d per lane; 3-stage shuffle reduce over g.
// Each wave writes its own o/denom partial (no cross-wave combine).
__global__ __launch_bounds__(256, 4) void k3_attn(
    const float* __restrict__ cK, const float* __restrict__ cV,
    const float* __restrict__ c_part, const float* __restrict__ inv,
    float* __restrict__ o_part, float* __restrict__ denom_part) {
  const int chunk = blockIdx.x;
  const int h = blockIdx.y;
  const int tid = threadIdx.x;
  const int wave = tid >> 6;
  const int lane = tid & 63;
  const int m8 = lane & 7;
  const int g = lane >> 3;
  const int d0 = g * 16;

  // q fragments: m = mi*8+m8, d = d0..d0+15  (sum quarters x inv, mat=0)
  float4 qa[4], qb[4];
  {
    float f[2][16];
#pragma unroll
    for (int mi = 0; mi < 2; ++mi)
#pragma unroll
      for (int j = 0; j < 16; ++j) f[mi][j] = 0.f;
#pragma unroll
    for (int qt = 0; qt < 4; ++qt) {
#pragma unroll
      for (int mi = 0; mi < 2; ++mi) {
        const int m = mi * 8 + m8;
        const float* cp = c_part + (((size_t)(qt * 16 + m)) << 12) + h * DD + d0;
#pragma unroll
        for (int j = 0; j < 4; ++j) {
          float4 t = ld4(cp + j * 4);
          f[mi][j * 4 + 0] += t.x;
          f[mi][j * 4 + 1] += t.y;
          f[mi][j * 4 + 2] += t.z;
          f[mi][j * 4 + 3] += t.w;
        }
      }
    }
    const float i0 = inv[m8];
    const float i1 = inv[8 + m8];
#pragma unroll
    for (int j = 0; j < 4; ++j) {
      qa[j] = make_float4(f[0][j * 4] * i0, f[0][j * 4 + 1] * i0,
                          f[0][j * 4 + 2] * i0, f[0][j * 4 + 3] * i0);
      qb[j] = make_float4(f[1][j * 4] * i1, f[1][j * 4 + 1] * i1,
                          f[1][j * 4 + 2] * i1, f[1][j * 4 + 3] * i1);
    }
  }

  float oac0[16], oac1[16];
#pragma unroll
  for (int j = 0; j < 16; ++j) { oac0[j] = 0.f; oac1[j] = 0.f; }
  float den0 = 0.f, den1 = 0.f;

  if (chunk < 32) {
    const size_t rowb = ((size_t)h * PP + chunk * 256 + wave * 64) * DD;
    const float* kb = cK + rowb + d0;
    const float* vb = cV + rowb + d0;
#pragma unroll 2
    for (int pi = 0; pi < 64; ++pi) {
      const float* kp = kb + pi * DD;
      float4 k0 = ld4(kp), k1 = ld4(kp + 4), k2 = ld4(kp + 8), k3 = ld4(kp + 12);
      const float* vp = vb + pi * DD;
      float4 v0 = ld4(vp), v1 = ld4(vp + 4), v2 = ld4(vp + 8), v3 = ld4(vp + 12);
      float c0 = dot4f(qa[0], k0) + dot4f(qa[1], k1) + dot4f(qa[2], k2) + dot4f(qa[3], k3);
      float c1 = dot4f(qb[0], k0) + dot4f(qb[1], k1) + dot4f(qb[2], k2) + dot4f(qb[3], k3);
#pragma unroll
      for (int off = 8; off < 64; off <<= 1) {
        c0 += __shfl_xor(c0, off, 64);
        c1 += __shfl_xor(c1, off, 64);
      }
      float e0 = __expf(c0), e1 = __expf(c1);
      den0 += e0; den1 += e1;
      accumv(oac0, e0, v0, v1, v2, v3);
      accumv(oac1, e1, v0, v1, v2, v3);
    }
  } else {
    // appended rows: k = mat1, v = mat2 quarter-sums x inv[p]
#pragma unroll
    for (int pi = 0; pi < 4; ++pi) {
      const int p = wave * 4 + pi;
      float kk[16], vv[16];
#pragma unroll
      for (int j = 0; j < 16; ++j) { kk[j] = 0.f; vv[j] = 0.f; }
#pragma unroll
      for (int qt = 0; qt < 4; ++qt) {
        const float* cpk = c_part + (((size_t)((4 + qt) * 16 + p)) << 12) + h * DD + d0;
        const float* cpv = c_part + (((size_t)((8 + qt) * 16 + p)) << 12) + h * DD + d0;
#pragma unroll
        for (int j = 0; j < 4; ++j) {
          float4 tk = ld4(cpk + j * 4);
          float4 tv = ld4(cpv + j * 4);
          kk[j * 4 + 0] += tk.x; kk[j * 4 + 1] += tk.y;
          kk[j * 4 + 2] += tk.z; kk[j * 4 + 3] += tk.w;
          vv[j * 4 + 0] += tv.x; vv[j * 4 + 1] += tv.y;
          vv[j * 4 + 2] += tv.z; vv[j * 4 + 3] += tv.w;
        }
      }
      const float ip = inv[p];
      float4 k0 = make_float4(kk[0] * ip, kk[1] * ip, kk[2] * ip, kk[3] * ip);
      float4 k1 = make_float4(kk[4] * ip, kk[5] * ip, kk[6] * ip, kk[7] * ip);
      float4 k2 = make_float4(kk[8] * ip, kk[9] * ip, kk[10] * ip, kk[11] * ip);
      float4 k3 = make_float4(kk[12] * ip, kk[13] * ip, kk[14] * ip, kk[15] * ip);
      float4 v0 = make_float4(vv[0] * ip, vv[1] * ip, vv[2] * ip, vv[3] * ip);
      float4 v1 = make_float4(vv[4] * ip, vv[5] * ip, vv[6] * ip, vv[7] * ip);
      float4 v2 = make_float4(vv[8] * ip, vv[9] * ip, vv[10] * ip, vv[11] * ip);
      float4 v3 = make_float4(vv[12] * ip, vv[13] * ip, vv[14] * ip, vv[15] * ip);
      float c0 = dot4f(qa[0], k0) + dot4f(qa[1], k1) + dot4f(qa[2], k2) + dot4f(qa[3], k3);
      float c1 = dot4f(qb[0], k0) + dot4f(qb[1], k1) + dot4f(qb[2], k2) + dot4f(qb[3], k3);
#pragma unroll
      for (int off = 8; off < 64; off <<= 1) {
        c0 += __shfl_xor(c0, off, 64);
        c1 += __shfl_xor(c1, off, 64);
      }
      float e0 = __expf(c0), e1 = __expf(c1);
      den0 += e0; den1 += e1;
      accumv(oac0, e0, v0, v1, v2, v3);
      accumv(oac1, e1, v0, v1, v2, v3);
    }
  }

  // per-wave partial out: wave-chunk index = (h*33+chunk)*4+wave
  const size_t wc = ((size_t)h * 33 + chunk) * 4 + wave;
  float* op0 = o_part + wc * 2048 + m8 * DD + d0;
  float* op1 = o_part + wc * 2048 + (8 + m8) * DD + d0;
#pragma unroll
  for (int j = 0; j < 4; ++j) {
    *(float4*)(op0 + j * 4) = make_float4(oac0[j * 4], oac0[j * 4 + 1],
                                          oac0[j * 4 + 2], oac0[j * 4 + 3]);
    *(float4*)(op1 + j * 4) = make_float4(oac1[j * 4], oac1[j * 4 + 1],
                                          oac1[j * 4 + 2], oac1[j * 4 + 3]);
  }
  if (g == 0) {
    denom_part[wc * 16 + m8] = den0;
    denom_part[wc * 16 + 8 + m8] = den1;
  }
}

// -------------------------------------------------------- K4: final reduce
// grid 256 = 32 h x 8 sub; one thread per output element; sum 132 wave-chunks.
__global__ void k4_final(const float* __restrict__ o_part,
                         const float* __restrict__ denom_part,
                         float* __restrict__ out) {
  const int b = blockIdx.x;
  const int h = b >> 3;
  const int sub = b & 7;
  const int tid = threadIdx.x;
  const int md = sub * 256 + tid;  // 0..2047
  __shared__ float dinv[2];
  if (tid == 0 || tid == 128) {
    const int mm = md >> 7;
    float s = 0.f;
    for (int c = 0; c < 132; ++c)
      s += denom_part[((size_t)h * 132 + c) * 16 + mm];
    dinv[tid >> 7] = 1.0f / s;
  }
  __syncthreads();
  float s = 0.f;
  for (int c = 0; c < 132; ++c)
    s += o_part[((size_t)h * 132 + c) * 2048 + md];
  const int m = md >> 7;
  const int d = md & 127;
  out[(size_t)m * NN + h * DD + d] = s * dinv[tid >> 7];
}

extern "C" void kernel_launch(void* const* d_in, const int* in_sizes, int n_in,
                              void* d_out, int out_size, void* d_ws, size_t ws_size,
                              hipStream_t stream) {
  (void)in_sizes; (void)n_in; (void)out_size; (void)ws_size;
  const float* X  = (const float*)d_in[0];
  const float* Wq = (const float*)d_in[1];
  const float* Wk = (const float*)d_in[2];
  const float* Wv = (const float*)d_in[3];
  const float* cK = (const float*)d_in[4];
  const float* cV = (const float*)d_in[5];
  float* out = (float*)d_out;
  float* ws = (float*)d_ws;

  float* inv        = ws;                   // 16
  float* c_part     = ws + 16;              // 3*4*16*4096 = 786432
  float* o_part     = c_part + 786432;      // 32*33*4*2048 = 8650752
  float* denom_part = o_part + 8650752;     // 32*132*16 = 67584
  // total 9,504,784 floats = 38.0 MB

  k1_rms<<<16, 256, 0, stream>>>(X, inv);
  k2_qkv<<<1536, 256, 0, stream>>>(X, Wq, Wk, Wv, c_part);
  k3_attn<<<dim3(33, 32), 256, 0, stream>>>(cK, cV, c_part, inv, o_part, denom_part);
  k4_final<<<256, 256, 0, stream>>>(o_part, denom_part, out);
}

// Round 3
// 478.772 us; speedup vs baseline: 1.1219x; 1.1219x over previous
//
#include <hip/hip_runtime.h>

#define NN 4096
#define HH 32
#define DD 128
#define MM 16
#define PP 8192

__device__ __forceinline__ float4 ld4(const float* p) { return *(const float4*)(p); }
__device__ __forceinline__ float dot4f(float4 a, float4 b) {
  return a.x * b.x + a.y * b.y + a.z * b.z + a.w * b.w;
}

// ---------------------------------------------------------------- K1: RMS inv
__global__ void k1_rms(const float* __restrict__ X, float* __restrict__ inv) {
  const int m = blockIdx.x;
  const int tid = threadIdx.x;
  float s = 0.f;
#pragma unroll
  for (int i = 0; i < 16; ++i) {
    float v = X[(size_t)m * NN + i * 256 + tid];
    s += v * v;
  }
#pragma unroll
  for (int off = 1; off < 64; off <<= 1) s += __shfl_xor(s, off, 64);
  __shared__ float red[4];
  if ((tid & 63) == 0) red[tid >> 6] = s;
  __syncthreads();
  if (tid == 0) {
    float t = red[0] + red[1] + red[2] + red[3];
    inv[m] = rsqrtf(t * (1.0f / (float)NN));
  }
}

// ------------------------------------------------- K2: QKV quarter partials
// grid 1536 = 3 mats x 4 k-quarters x 128 row-blocks(32 rows). block 256.
// W staged global->regs->LDS double-buffered (4-row x 1024-k tiles, 16 KB);
// staging loads fully coalesced. X in registers. lane=(m4,g16): 4 m x 16 k.
__global__ __launch_bounds__(256, 3) void k2_qkv(
    const float* __restrict__ X, const float* __restrict__ Wq,
    const float* __restrict__ Wk, const float* __restrict__ Wv,
    float* __restrict__ c_part) {
  __shared__ float wt[2][4][1024];     // 32 KB double buffer
  __shared__ float lds_c[4][32][17];   // wave partial combine
  const int b = blockIdx.x;
  const int mat = b >> 9;
  const int qt = (b >> 7) & 3;
  const int rb = b & 127;              // rows rb*32 .. +31
  const float* W = (mat == 0) ? Wq : (mat == 1) ? Wk : Wv;
  const int tid = threadIdx.x;
  const int wave = tid >> 6;
  const int lane = tid & 63;
  const int m4 = lane & 3;
  const int g = lane >> 2;
  const int kwin = wave * 256 + g * 16;       // within the 1024-k quarter
  const int kbase = qt * 1024 + kwin;         // global k offset

  float4 xr[4][4];  // X[m = mi*4+m4][16 k slice]
#pragma unroll
  for (int mi = 0; mi < 4; ++mi) {
    const float* xp = X + (size_t)(mi * 4 + m4) * NN + kbase;
#pragma unroll
    for (int j = 0; j < 4; ++j) xr[mi][j] = ld4(xp + j * 4);
  }

  // staging: tile = 4 rows x 1024 floats = 1024 float4; 4 per thread
  const float* Wbase = W + (size_t)(rb * 32) * NN + qt * 1024;
  float4 rw[4];
#pragma unroll
  for (int i = 0; i < 4; ++i) {
    const int id = tid + i * 256;
    rw[i] = *((const float4*)(Wbase + (size_t)(id >> 8) * NN) + (id & 255));
  }

  for (int tt = 0; tt < 8; ++tt) {
    __syncthreads();
#pragma unroll
    for (int i = 0; i < 4; ++i)
      ((float4*)wt[tt & 1])[tid + i * 256] = rw[i];
    __syncthreads();
    if (tt < 7) {
      const float* Wn = Wbase + (size_t)((tt + 1) * 4) * NN;
#pragma unroll
      for (int i = 0; i < 4; ++i) {
        const int id = tid + i * 256;
        rw[i] = *((const float4*)(Wn + (size_t)(id >> 8) * NN) + (id & 255));
      }
    }
    // compute this tile's 4 rows
    float acc[4][4];
#pragma unroll
    for (int r = 0; r < 4; ++r)
#pragma unroll
      for (int mi = 0; mi < 4; ++mi) acc[r][mi] = 0.f;
#pragma unroll
    for (int r = 0; r < 4; ++r) {
      const float* wp = wt[tt & 1][r] + kwin;
      float4 w0 = ld4(wp), w1 = ld4(wp + 4), w2 = ld4(wp + 8), w3 = ld4(wp + 12);
#pragma unroll
      for (int mi = 0; mi < 4; ++mi)
        acc[r][mi] += dot4f(xr[mi][0], w0) + dot4f(xr[mi][1], w1) +
                      dot4f(xr[mi][2], w2) + dot4f(xr[mi][3], w3);
    }
#pragma unroll
    for (int off = 4; off < 64; off <<= 1)
#pragma unroll
      for (int r = 0; r < 4; ++r)
#pragma unroll
        for (int mi = 0; mi < 4; ++mi)
          acc[r][mi] += __shfl_xor(acc[r][mi], off, 64);
    if (g == 0) {
#pragma unroll
      for (int r = 0; r < 4; ++r)
#pragma unroll
        for (int mi = 0; mi < 4; ++mi)
          lds_c[wave][tt * 4 + r][mi * 4 + m4] = acc[r][mi];
    }
  }
  __syncthreads();
  // combine 4 waves' k-sub-slices -> quarter partial [mat*4+qt][m][4096]
#pragma unroll
  for (int i = 0; i < 2; ++i) {
    const int idx = i * 256 + tid;
    const int l = idx >> 4;   // local row 0..31
    const int m = idx & 15;
    float s = lds_c[0][l][m] + lds_c[1][l][m] + lds_c[2][l][m] + lds_c[3][l][m];
    c_part[(((size_t)(mat * 4 + qt) * 16 + m) << 12) + (rb * 32 + l)] = s;
  }
}

// --------------------------------------- K2b: combine quarters, scale by inv
// qkv[mat][m][j=h*128+d] = inv[m] * sum_qt c_part[mat][qt][m][j]
__global__ void k2b_combine(const float* __restrict__ c_part,
                            const float* __restrict__ inv,
                            float* __restrict__ qkv) {
  const int t = blockIdx.x * 256 + threadIdx.x;  // 0..196607
  const int mat = t >> 16;
  const int r = t & 65535;
  const int m = r >> 12;
  const int j = r & 4095;
  float s = 0.f;
#pragma unroll
  for (int qt = 0; qt < 4; ++qt)
    s += c_part[(((size_t)(mat * 4 + qt) * 16 + m) << 12) + j];
  qkv[(((size_t)(mat * 16 + m)) << 12) + j] = s * inv[m];
}

// ------------------------------------------------- K3: attention partials
// grid 512 = 32 h x 16 seg (512 rows each; exactly 2 blocks/CU, 1 generation).
// K/V staged global->regs->LDS double-buffered in 32-row tiles (32 KB).
// lane=(m8,g8): 2 m x 16 d; 3-stage shuffle reduce; per-wave partial out.
// Block with seg==(h&15) also handles the 16 appended rows from qkv.
__global__ __launch_bounds__(256, 2) void k3_attn(
    const float* __restrict__ cK, const float* __restrict__ cV,
    const float* __restrict__ qkv, float* __restrict__ o_part,
    float* __restrict__ den_part) {
  __shared__ float sK[2][4096];
  __shared__ float sV[2][4096];
  const int b = blockIdx.x;
  const int h = b >> 4;
  const int seg = b & 15;
  const int tid = threadIdx.x;
  const int wave = tid >> 6;
  const int lane = tid & 63;
  const int m8 = lane & 7;
  const int g = lane >> 3;
  const int d0 = g * 16;

  // q fragments for m = m8 and m8+8
  float4 q0[4], q1[4];
  {
    const float* qa = qkv + (size_t)m8 * NN + h * DD + d0;
    const float* qb = qkv + (size_t)(m8 + 8) * NN + h * DD + d0;
#pragma unroll
    for (int j = 0; j < 4; ++j) { q0[j] = ld4(qa + j * 4); q1[j] = ld4(qb + j * 4); }
  }
  float o0[16], o1[16];
#pragma unroll
  for (int j = 0; j < 16; ++j) { o0[j] = 0.f; o1[j] = 0.f; }
  float den0 = 0.f, den1 = 0.f;

  const float4* gK = (const float4*)(cK + ((size_t)h * PP + seg * 512) * DD);
  const float4* gV = (const float4*)(cV + ((size_t)h * PP + seg * 512) * DD);

  float4 rk[4], rv[4];
#pragma unroll
  for (int i = 0; i < 4; ++i) { rk[i] = gK[tid + i * 256]; rv[i] = gV[tid + i * 256]; }

  for (int t = 0; t < 16; ++t) {
    __syncthreads();
#pragma unroll
    for (int i = 0; i < 4; ++i) {
      ((float4*)sK[t & 1])[tid + i * 256] = rk[i];
      ((float4*)sV[t & 1])[tid + i * 256] = rv[i];
    }
    __syncthreads();
    if (t < 15) {
      const int base = (t + 1) * 1024;
#pragma unroll
      for (int i = 0; i < 4; ++i) {
        rk[i] = gK[base + tid + i * 256];
        rv[i] = gV[base + tid + i * 256];
      }
    }
    const float* bK = sK[t & 1];
    const float* bV = sV[t & 1];
#pragma unroll
    for (int pi = 0; pi < 8; ++pi) {
      const int p = wave * 8 + pi;
      const float* kp = bK + p * DD + d0;
      float4 k0 = ld4(kp), k1 = ld4(kp + 4), k2 = ld4(kp + 8), k3 = ld4(kp + 12);
      float c0 = dot4f(q0[0], k0) + dot4f(q0[1], k1) + dot4f(q0[2], k2) + dot4f(q0[3], k3);
      float c1 = dot4f(q1[0], k0) + dot4f(q1[1], k1) + dot4f(q1[2], k2) + dot4f(q1[3], k3);
#pragma unroll
      for (int off = 8; off < 64; off <<= 1) {
        c0 += __shfl_xor(c0, off, 64);
        c1 += __shfl_xor(c1, off, 64);
      }
      float e0 = __expf(c0), e1 = __expf(c1);
      den0 += e0; den1 += e1;
      const float* vp = bV + p * DD + d0;
      float4 v0 = ld4(vp), v1 = ld4(vp + 4), v2 = ld4(vp + 8), v3 = ld4(vp + 12);
      o0[0] += e0 * v0.x;  o0[1] += e0 * v0.y;  o0[2] += e0 * v0.z;  o0[3] += e0 * v0.w;
      o0[4] += e0 * v1.x;  o0[5] += e0 * v1.y;  o0[6] += e0 * v1.z;  o0[7] += e0 * v1.w;
      o0[8] += e0 * v2.x;  o0[9] += e0 * v2.y;  o0[10] += e0 * v2.z; o0[11] += e0 * v2.w;
      o0[12] += e0 * v3.x; o0[13] += e0 * v3.y; o0[14] += e0 * v3.z; o0[15] += e0 * v3.w;
      o1[0] += e1 * v0.x;  o1[1] += e1 * v0.y;  o1[2] += e1 * v0.z;  o1[3] += e1 * v0.w;
      o1[4] += e1 * v1.x;  o1[5] += e1 * v1.y;  o1[6] += e1 * v1.z;  o1[7] += e1 * v1.w;
      o1[8] += e1 * v2.x;  o1[9] += e1 * v2.y;  o1[10] += e1 * v2.z; o1[11] += e1 * v2.w;
      o1[12] += e1 * v3.x; o1[13] += e1 * v3.y; o1[14] += e1 * v3.z; o1[15] += e1 * v3.w;
    }
  }

  // appended 16 rows (k = qkv mat1, v = qkv mat2), one block per head
  if (seg == (h & 15)) {
    __syncthreads();
    const int r0 = tid >> 5;     // 0..7
    const int c = tid & 31;
#pragma unroll
    for (int rr = 0; rr < 2; ++rr) {
      const int p = rr * 8 + r0;
      ((float4*)sK[0])[p * 32 + c] =
          *((const float4*)(qkv + (size_t)(16 + p) * NN + h * DD) + c);
      ((float4*)sV[0])[p * 32 + c] =
          *((const float4*)(qkv + (size_t)(32 + p) * NN + h * DD) + c);
    }
    __syncthreads();
#pragma unroll
    for (int pi = 0; pi < 4; ++pi) {
      const int p = wave * 4 + pi;
      const float* kp = sK[0] + p * DD + d0;
      float4 k0 = ld4(kp), k1 = ld4(kp + 4), k2 = ld4(kp + 8), k3 = ld4(kp + 12);
      float c0 = dot4f(q0[0], k0) + dot4f(q0[1], k1) + dot4f(q0[2], k2) + dot4f(q0[3], k3);
      float c1 = dot4f(q1[0], k0) + dot4f(q1[1], k1) + dot4f(q1[2], k2) + dot4f(q1[3], k3);
#pragma unroll
      for (int off = 8; off < 64; off <<= 1) {
        c0 += __shfl_xor(c0, off, 64);
        c1 += __shfl_xor(c1, off, 64);
      }
      float e0 = __expf(c0), e1 = __expf(c1);
      den0 += e0; den1 += e1;
      const float* vp = sV[0] + p * DD + d0;
      float4 v0 = ld4(vp), v1 = ld4(vp + 4), v2 = ld4(vp + 8), v3 = ld4(vp + 12);
      o0[0] += e0 * v0.x;  o0[1] += e0 * v0.y;  o0[2] += e0 * v0.z;  o0[3] += e0 * v0.w;
      o0[4] += e0 * v1.x;  o0[5] += e0 * v1.y;  o0[6] += e0 * v1.z;  o0[7] += e0 * v1.w;
      o0[8] += e0 * v2.x;  o0[9] += e0 * v2.y;  o0[10] += e0 * v2.z; o0[11] += e0 * v2.w;
      o0[12] += e0 * v3.x; o0[13] += e0 * v3.y; o0[14] += e0 * v3.z; o0[15] += e0 * v3.w;
      o1[0] += e1 * v0.x;  o1[1] += e1 * v0.y;  o1[2] += e1 * v0.z;  o1[3] += e1 * v0.w;
      o1[4] += e1 * v1.x;  o1[5] += e1 * v1.y;  o1[6] += e1 * v1.z;  o1[7] += e1 * v1.w;
      o1[8] += e1 * v2.x;  o1[9] += e1 * v2.y;  o1[10] += e1 * v2.z; o1[11] += e1 * v2.w;
      o1[12] += e1 * v3.x; o1[13] += e1 * v3.y; o1[14] += e1 * v3.z; o1[15] += e1 * v3.w;
    }
  }

  // write per-wave partials
  float* op = o_part + ((size_t)b * 4 + wave) * 2048;
#pragma unroll
  for (int j = 0; j < 4; ++j) {
    *(float4*)(op + m8 * DD + d0 + j * 4) =
        make_float4(o0[j * 4], o0[j * 4 + 1], o0[j * 4 + 2], o0[j * 4 + 3]);
    *(float4*)(op + (m8 + 8) * DD + d0 + j * 4) =
        make_float4(o1[j * 4], o1[j * 4 + 1], o1[j * 4 + 2], o1[j * 4 + 3]);
  }
  if (g == 0) {
    den_part[((size_t)b * 4 + wave) * 16 + m8] = den0;
    den_part[((size_t)b * 4 + wave) * 16 + 8 + m8] = den1;
  }
}

// -------------------------------------------------------- K4: final reduce
// grid 256 = 32 h x 8 sub; sum 64 wave-partials per head, divide, write out.
__global__ void k4_final(const float* __restrict__ o_part,
                         const float* __restrict__ den_part,
                         float* __restrict__ out) {
  const int b = blockIdx.x;
  const int h = b >> 3;
  const int tid = threadIdx.x;
  const int idx = (b & 7) * 256 + tid;  // 0..2047 = m*128+d
  __shared__ float dinv[16];
  if (tid < 16) {
    float s = 0.f;
    for (int j = 0; j < 64; ++j) s += den_part[(size_t)h * 1024 + j * 16 + tid];
    dinv[tid] = 1.0f / s;
  }
  __syncthreads();
  float s = 0.f;
  for (int j = 0; j < 64; ++j) s += o_part[(size_t)h * 131072 + j * 2048 + idx];
  const int m = idx >> 7;
  const int d = idx & 127;
  out[(size_t)m * NN + h * DD + d] = s * dinv[m];
}

extern "C" void kernel_launch(void* const* d_in, const int* in_sizes, int n_in,
                              void* d_out, int out_size, void* d_ws, size_t ws_size,
                              hipStream_t stream) {
  (void)in_sizes; (void)n_in; (void)out_size; (void)ws_size;
  const float* X  = (const float*)d_in[0];
  const float* Wq = (const float*)d_in[1];
  const float* Wk = (const float*)d_in[2];
  const float* Wv = (const float*)d_in[3];
  const float* cK = (const float*)d_in[4];
  const float* cV = (const float*)d_in[5];
  float* out = (float*)d_out;
  float* ws = (float*)d_ws;

  float* inv      = ws;                  // 16
  float* c_part   = ws + 16;             // 3*4*16*4096 = 786432
  float* qkv      = c_part + 786432;     // 3*16*4096   = 196608
  float* o_part   = qkv + 196608;        // 512*4*2048  = 4194304
  float* den_part = o_part + 4194304;    // 512*4*16    = 32768
  // total ~20.8 MB

  k1_rms<<<16, 256, 0, stream>>>(X, inv);
  k2_qkv<<<1536, 256, 0, stream>>>(X, Wq, Wk, Wv, c_part);
  k2b_combine<<<768, 256, 0, stream>>>(c_part, inv, qkv);
  k3_attn<<<dim3(512), 256, 0, stream>>>(cK, cV, qkv, o_part, den_part);
  k4_final<<<256, 256, 0, stream>>>(o_part, den_part, out);
}